// Round 10
// baseline (151.450 us; speedup 1.0000x reference)
//
#include <hip/hip_runtime.h>

#define NB 32
#define N0 20000
#define N1 10000
#define N2 10000
#define KC_A 8
#define KC_B 16
#define NBINS 4096
#define NBLK_TOTAL (2048 + 256)
#define SENT 3.0e4f        // sentinel coord: per-pair contribution ~ -1e-10

// grid = 256 B-role blocks (binned ext 1-D part) + 2048 A-role blocks
// (exact beta_0, 4 points/lane). All atomicAdd into memset-zeroed out[0..4096];
// out[4096] doubles as a completion counter; last block computes tpl.
__global__ __launch_bounds__(256, 8) void hat_kernel(
    const float* __restrict__ up0, const float* __restrict__ down0,
    const float* __restrict__ ext0, const float* __restrict__ ext1,
    const float* __restrict__ centers, const float* __restrict__ radius,
    float* __restrict__ out)
{
    const int tid  = threadIdx.x;
    const int lane = tid & 63;
    const int wave = tid >> 6;
    const float r  = fabsf(radius[0]);
    const float nr = -r;

    __shared__ unsigned hist[NBINS];     // 16 KB (B-role only)
    __shared__ float    red[4 * KC_B];
    __shared__ int      is_last;

    if (blockIdx.x < 256) {
        // ================= B-role: ext points, 1-D binned (R9-validated) ====
        const int id   = blockIdx.x;
        const int cc   = id & 3;
        const int side = (id >> 2) & 1;
        const int b    = id >> 3;
        const int cbase = cc * KC_B;

        for (int j = tid; j < NBINS; j += 256) hist[j] = 0;
        __syncthreads();

        const float2* e0 = (const float2*)(ext0 + (size_t)b * (N1*2));
        const float2* e1 = (const float2*)(ext1 + (size_t)b * (N2*2));
        for (int i = tid; i < N1; i += 256) {
            const float2 q0 = e0[i];
            const float2 q1 = e1[i];
            const float vv0 = (side == 0) ? q0.y : q0.x;
            const float vv1 = (side == 0) ? q1.y : q1.x;
            int b0 = (int)(vv0 * (float)NBINS);
            int b1 = (int)(vv1 * (float)NBINS);
            b0 = min(max(b0, 0), NBINS - 1);
            b1 = min(max(b1, 0), NBINS - 1);
            atomicAdd(&hist[b0], 1u);
            atomicAdd(&hist[b1], 1u);
        }
        __syncthreads();

        float Ak[KC_B], mk[KC_B];
        #pragma unroll
        for (int k = 0; k < KC_B; ++k) {
            const float cx = centers[2*(cbase+k)];
            const float cy = centers[2*(cbase+k)+1];
            Ak[k] = fabsf(1.0f - (cx + cy));
            mk[k] = 0.5f * (1.0f + (cx - cy));
        }

        float part[KC_B];
        #pragma unroll
        for (int k = 0; k < KC_B; ++k) part[k] = 0.f;

        #pragma unroll
        for (int jj = 0; jj < NBINS/256; ++jj) {
            const int j = jj*256 + tid;
            const float cntf = (float)hist[j];
            const float vvj  = ((float)j + 0.5f) * (1.0f/(float)NBINS);
            #pragma unroll
            for (int k = 0; k < KC_B; ++k) {
                const float s  = vvj - mk[k];
                const float tt = fmaxf(Ak[k], 2.0f*fabsf(s));
                const float d1 = 1.0f + tt;
                const float rn = r - tt;
                const float d2 = 1.0f + fabsf(rn);
                const float rc = __builtin_amdgcn_rcpf(d1 * d2);
                part[k] = fmaf(cntf * (d2 - d1), rc, part[k]);
            }
        }

        // KC=16 butterfly (R6-validated)
        {
            #pragma unroll
            for (int k = 0; k < 8; ++k) {
                const bool hi = lane & 32;
                const float send = hi ? part[k]   : part[k+8];
                const float keep = hi ? part[k+8] : part[k];
                part[k] = keep + __shfl_xor(send, 32, 64);
            }
            #pragma unroll
            for (int k = 0; k < 4; ++k) {
                const bool hi = lane & 16;
                const float send = hi ? part[k]   : part[k+4];
                const float keep = hi ? part[k+4] : part[k];
                part[k] = keep + __shfl_xor(send, 16, 64);
            }
            #pragma unroll
            for (int k = 0; k < 2; ++k) {
                const bool hi = lane & 8;
                const float send = hi ? part[k]   : part[k+2];
                const float keep = hi ? part[k+2] : part[k];
                part[k] = keep + __shfl_xor(send, 8, 64);
            }
            {
                const bool hi = lane & 4;
                const float send = hi ? part[0] : part[1];
                const float keep = hi ? part[1] : part[0];
                part[0] = keep + __shfl_xor(send, 4, 64);
            }
            part[0] += __shfl_xor(part[0], 2, 64);
            part[0] += __shfl_xor(part[0], 1, 64);
        }
        if ((lane & 3) == 0) red[wave * KC_B + (lane >> 2)] = part[0];
        __syncthreads();
        if (tid < KC_B) {
            const float s = red[tid] + red[KC_B + tid] + red[2*KC_B + tid] + red[3*KC_B + tid];
            atomicAdd(&out[b*128 + side*64 + cbase + tid], s);
        }
    } else {
        // ========== A-role: beta_0 exact f32, 4 points/lane ==========
        const int bid    = blockIdx.x - 256;
        const int tchunk = bid & 3;
        const int cc     = (bid >> 2) & 7;
        const int side   = (bid >> 5) & 1;
        const int b      = bid >> 6;
        const int cbase  = cc * KC_A;

        float uc[KC_A], vc[KC_A];
        #pragma unroll
        for (int k = 0; k < KC_A; ++k) {
            const float cx = centers[2*(cbase+k)];
            const float cy = centers[2*(cbase+k)+1];
            uc[k] = cx + cy;
            vc[k] = cx - cy;
        }

        const float4* base0 = (const float4*)((side == 0 ? up0 : down0) + (size_t)b * (N0*2));

        float acc[KC_A][4];
        #pragma unroll
        for (int k = 0; k < KC_A; ++k)
            #pragma unroll
            for (int p = 0; p < 4; ++p) acc[k][p] = 0.f;

        // 10000 float4 per (b,side); 2 float4 (4 pts) per lane per iter;
        // 79*128 = 10112 covers all, remainder -> sentinel.
        for (int t = tchunk*4 + wave; t < 79; t += 16) {
            const int i0 = t*128 + 2*lane;
            float u[4], v[4];
            if (i0 < 10000) {
                const float4 q0 = base0[i0];
                const float4 q1 = base0[i0+1];
                u[0] = q0.x + q0.y;  v[0] = q0.x - q0.y;
                u[1] = q0.z + q0.w;  v[1] = q0.z - q0.w;
                u[2] = q1.x + q1.y;  v[2] = q1.x - q1.y;
                u[3] = q1.z + q1.w;  v[3] = q1.z - q1.w;
            } else {
                #pragma unroll
                for (int p = 0; p < 4; ++p) { u[p] = SENT; v[p] = 0.f; }
            }

            #pragma unroll
            for (int k = 0; k < KC_A; ++k) {
                #pragma unroll
                for (int p = 0; p < 4; ++p) {
                    const float du = u[p] - uc[k];
                    const float dv = v[p] - vc[k];
                    const float tt = fmaxf(fabsf(du), fabsf(dv)); // L1 via Linf
                    const float d1 = 1.0f + tt;
                    // num = |r-n| - n == max(r - 2n, -r)
                    const float num = fmaxf(fmaf(-2.0f, tt, r), nr);
                    const float d2 = d1 + num;                    // 1 + |r-n|
                    const float rc = __builtin_amdgcn_rcpf(d1 * d2);
                    acc[k][p] = fmaf(num, rc, acc[k][p]);
                }
            }
        }

        float a1[KC_A];
        #pragma unroll
        for (int k = 0; k < KC_A; ++k)
            a1[k] = (acc[k][0] + acc[k][1]) + (acc[k][2] + acc[k][3]);

        // KC=8 butterfly (R7/R8-validated)
        {
            #pragma unroll
            for (int k = 0; k < 4; ++k) {
                const bool hi = lane & 32;
                const float send = hi ? a1[k]   : a1[k+4];
                const float keep = hi ? a1[k+4] : a1[k];
                a1[k] = keep + __shfl_xor(send, 32, 64);
            }
            #pragma unroll
            for (int k = 0; k < 2; ++k) {
                const bool hi = lane & 16;
                const float send = hi ? a1[k]   : a1[k+2];
                const float keep = hi ? a1[k+2] : a1[k];
                a1[k] = keep + __shfl_xor(send, 16, 64);
            }
            {
                const bool hi = lane & 8;
                const float send = hi ? a1[0] : a1[1];
                const float keep = hi ? a1[1] : a1[0];
                a1[0] = keep + __shfl_xor(send, 8, 64);
            }
            a1[0] += __shfl_xor(a1[0], 4, 64);
            a1[0] += __shfl_xor(a1[0], 2, 64);
            a1[0] += __shfl_xor(a1[0], 1, 64);
        }
        if ((lane & 7) == 0) red[wave * KC_A + (lane >> 3)] = a1[0];
        __syncthreads();
        if (tid < KC_A) {
            const float s = red[tid] + red[KC_A + tid] + red[2*KC_A + tid] + red[3*KC_A + tid];
            atomicAdd(&out[b*128 + side*64 + cbase + tid], s);
        }
    }

    // ---- completion counter at out[4096]; last block computes tpl ----
    __syncthreads();                 // block's atomicAdds issued
    if (tid == 0) {
        __threadfence();             // release: adds visible before count
        const int old = atomicAdd((int*)&out[NB*128], 1);
        is_last = (old == NBLK_TOTAL - 1);
    }
    __syncthreads();
    if (is_last) {
        if (tid == 0) __threadfence();   // acquire
        __syncthreads();
        float s = 0.f;
        for (int i = tid; i < NB*64; i += 256) {
            const int bb = i >> 6, k = i & 63;
            const float d = out[bb*128 + k] - out[bb*128 + 64 + k];
            s = fmaf(d, d, s);
        }
        s += __shfl_xor(s, 32, 64);
        s += __shfl_xor(s, 16, 64);
        s += __shfl_xor(s, 8, 64);
        s += __shfl_xor(s, 4, 64);
        s += __shfl_xor(s, 2, 64);
        s += __shfl_xor(s, 1, 64);
        if (lane == 0) red[wave] = s;
        __syncthreads();
        if (tid == 0) {
            const float tot = (red[0] + red[1]) + (red[2] + red[3]);
            out[NB*128] = -tot;
        }
    }
}

extern "C" void kernel_launch(void* const* d_in, const int* in_sizes, int n_in,
                              void* d_out, int out_size, void* d_ws, size_t ws_size,
                              hipStream_t stream) {
    const float* up0     = (const float*)d_in[0];
    const float* down0   = (const float*)d_in[1];
    const float* ext0    = (const float*)d_in[2];
    const float* ext1    = (const float*)d_in[3];
    const float* centers = (const float*)d_in[4];
    const float* radius  = (const float*)d_in[5];
    float* out = (float*)d_out;

    // zero accumulators + counter slot (harness poisons d_out with 0xAA)
    hipMemsetAsync(out, 0, (NB * 128 + 1) * sizeof(float), stream);

    hat_kernel<<<dim3(NBLK_TOTAL), dim3(256), 0, stream>>>(
        up0, down0, ext0, ext1, centers, radius, out);
}

// Round 11
// 112.753 us; speedup vs baseline: 1.3432x; 1.3432x over previous
//
#include <hip/hip_runtime.h>

#define NB 32
#define N0 20000
#define N1 10000
#define N2 10000
#define KC_A 8
#define KC_B 16
#define NBINS 4096
#define SENT 3.0e4f        // sentinel coord: per-pair contribution ~ -1e-10

__device__ __forceinline__ float sgpr(float x) {
    return __int_as_float(__builtin_amdgcn_readfirstlane(__float_as_int(x)));
}

// grid = 256 B-role blocks (binned ext 1-D part) + 2048 A-role blocks
// (exact beta_0, 2 points/lane). All atomicAdd into memset-zeroed out[0..4095].
__global__ __launch_bounds__(256, 8) void hat_kernel(
    const float* __restrict__ up0, const float* __restrict__ down0,
    const float* __restrict__ ext0, const float* __restrict__ ext1,
    const float* __restrict__ centers, const float* __restrict__ radius,
    float* __restrict__ out)
{
    const int tid  = threadIdx.x;
    const int lane = tid & 63;
    const int wave = tid >> 6;
    const float r  = sgpr(fabsf(radius[0]));
    const float nr = -r;

    __shared__ unsigned hist[NBINS];     // 16 KB (B-role only)
    __shared__ float    red[4 * KC_B];

    if (blockIdx.x < 256) {
        // ================= B-role: ext points, 1-D binned (R9-validated) ====
        const int id   = blockIdx.x;
        const int cc   = id & 3;
        const int side = (id >> 2) & 1;
        const int b    = id >> 3;
        const int cbase = cc * KC_B;

        for (int j = tid; j < NBINS; j += 256) hist[j] = 0;
        __syncthreads();

        const float2* e0 = (const float2*)(ext0 + (size_t)b * (N1*2));
        const float2* e1 = (const float2*)(ext1 + (size_t)b * (N2*2));
        for (int i = tid; i < N1; i += 256) {
            const float2 q0 = e0[i];
            const float2 q1 = e1[i];
            const float vv0 = (side == 0) ? q0.y : q0.x;
            const float vv1 = (side == 0) ? q1.y : q1.x;
            int b0 = (int)(vv0 * (float)NBINS);
            int b1 = (int)(vv1 * (float)NBINS);
            b0 = min(max(b0, 0), NBINS - 1);
            b1 = min(max(b1, 0), NBINS - 1);
            atomicAdd(&hist[b0], 1u);
            atomicAdd(&hist[b1], 1u);
        }
        __syncthreads();

        // center constants in SGPRs (wave-uniform)
        float Ak[KC_B], mk[KC_B];
        #pragma unroll
        for (int k = 0; k < KC_B; ++k) {
            const float cx = centers[2*(cbase+k)];
            const float cy = centers[2*(cbase+k)+1];
            Ak[k] = sgpr(fabsf(1.0f - (cx + cy)));
            mk[k] = sgpr(0.5f * (1.0f + (cx - cy)));
        }

        float part[KC_B];
        #pragma unroll
        for (int k = 0; k < KC_B; ++k) part[k] = 0.f;

        #pragma unroll
        for (int jj = 0; jj < NBINS/256; ++jj) {
            const int j = jj*256 + tid;
            const float cntf = (float)hist[j];
            const float vvj  = ((float)j + 0.5f) * (1.0f/(float)NBINS);
            #pragma unroll
            for (int k = 0; k < KC_B; ++k) {
                const float s  = vvj - mk[k];
                const float tt = fmaxf(Ak[k], 2.0f*fabsf(s));
                const float d1 = 1.0f + tt;
                const float rn = r - tt;
                const float d2 = 1.0f + fabsf(rn);
                const float rc = __builtin_amdgcn_rcpf(d1 * d2);
                part[k] = fmaf(cntf * (d2 - d1), rc, part[k]);
            }
        }

        // KC=16 butterfly (R6-validated)
        {
            #pragma unroll
            for (int k = 0; k < 8; ++k) {
                const bool hi = lane & 32;
                const float send = hi ? part[k]   : part[k+8];
                const float keep = hi ? part[k+8] : part[k];
                part[k] = keep + __shfl_xor(send, 32, 64);
            }
            #pragma unroll
            for (int k = 0; k < 4; ++k) {
                const bool hi = lane & 16;
                const float send = hi ? part[k]   : part[k+4];
                const float keep = hi ? part[k+4] : part[k];
                part[k] = keep + __shfl_xor(send, 16, 64);
            }
            #pragma unroll
            for (int k = 0; k < 2; ++k) {
                const bool hi = lane & 8;
                const float send = hi ? part[k]   : part[k+2];
                const float keep = hi ? part[k+2] : part[k];
                part[k] = keep + __shfl_xor(send, 8, 64);
            }
            {
                const bool hi = lane & 4;
                const float send = hi ? part[0] : part[1];
                const float keep = hi ? part[1] : part[0];
                part[0] = keep + __shfl_xor(send, 4, 64);
            }
            part[0] += __shfl_xor(part[0], 2, 64);
            part[0] += __shfl_xor(part[0], 1, 64);
        }
        if ((lane & 3) == 0) red[wave * KC_B + (lane >> 2)] = part[0];
        __syncthreads();
        if (tid < KC_B) {
            const float s = red[tid] + red[KC_B + tid] + red[2*KC_B + tid] + red[3*KC_B + tid];
            atomicAdd(&out[b*128 + side*64 + cbase + tid], s);
        }
    } else {
        // ========== A-role: beta_0 exact f32, 2 points/lane ==========
        const int bid    = blockIdx.x - 256;
        const int tchunk = bid & 3;
        const int cc     = (bid >> 2) & 7;
        const int side   = (bid >> 5) & 1;
        const int b      = bid >> 6;
        const int cbase  = cc * KC_A;

        // center constants in SGPRs (wave-uniform)
        float uc[KC_A], vc[KC_A];
        #pragma unroll
        for (int k = 0; k < KC_A; ++k) {
            const float cx = centers[2*(cbase+k)];
            const float cy = centers[2*(cbase+k)+1];
            uc[k] = sgpr(cx + cy);
            vc[k] = sgpr(cx - cy);
        }

        const float4* base0 = (const float4*)((side == 0 ? up0 : down0) + (size_t)b * (N0*2));

        float acc[KC_A][2];
        #pragma unroll
        for (int k = 0; k < KC_A; ++k) { acc[k][0] = 0.f; acc[k][1] = 0.f; }

        // 10000 float4 per (b,side); 1 float4 (2 pts) per lane per iter
        for (int t = tchunk*4 + wave; t < 157; t += 16) {
            const int i = t*64 + lane;
            float u0, v0, u1, v1;
            if (i < 10000) {
                const float4 q = base0[i];
                u0 = q.x + q.y;  v0 = q.x - q.y;
                u1 = q.z + q.w;  v1 = q.z - q.w;
            } else {
                u0 = SENT; v0 = 0.f; u1 = SENT; v1 = 0.f;
            }

            #pragma unroll
            for (int k = 0; k < KC_A; ++k) {
                {
                    const float du = u0 - uc[k];
                    const float dv = v0 - vc[k];
                    const float tt = fmaxf(fabsf(du), fabsf(dv)); // L1 via Linf
                    const float d1 = 1.0f + tt;
                    const float num = fmaxf(fmaf(-2.0f, tt, r), nr); // |r-n|-n
                    const float d2 = d1 + num;                       // 1+|r-n|
                    const float rc = __builtin_amdgcn_rcpf(d1 * d2);
                    acc[k][0] = fmaf(num, rc, acc[k][0]);
                }
                {
                    const float du = u1 - uc[k];
                    const float dv = v1 - vc[k];
                    const float tt = fmaxf(fabsf(du), fabsf(dv));
                    const float d1 = 1.0f + tt;
                    const float num = fmaxf(fmaf(-2.0f, tt, r), nr);
                    const float d2 = d1 + num;
                    const float rc = __builtin_amdgcn_rcpf(d1 * d2);
                    acc[k][1] = fmaf(num, rc, acc[k][1]);
                }
            }
        }

        float a1[KC_A];
        #pragma unroll
        for (int k = 0; k < KC_A; ++k) a1[k] = acc[k][0] + acc[k][1];

        // KC=8 butterfly (R7/R8-validated)
        {
            #pragma unroll
            for (int k = 0; k < 4; ++k) {
                const bool hi = lane & 32;
                const float send = hi ? a1[k]   : a1[k+4];
                const float keep = hi ? a1[k+4] : a1[k];
                a1[k] = keep + __shfl_xor(send, 32, 64);
            }
            #pragma unroll
            for (int k = 0; k < 2; ++k) {
                const bool hi = lane & 16;
                const float send = hi ? a1[k]   : a1[k+2];
                const float keep = hi ? a1[k+2] : a1[k];
                a1[k] = keep + __shfl_xor(send, 16, 64);
            }
            {
                const bool hi = lane & 8;
                const float send = hi ? a1[0] : a1[1];
                const float keep = hi ? a1[1] : a1[0];
                a1[0] = keep + __shfl_xor(send, 8, 64);
            }
            a1[0] += __shfl_xor(a1[0], 4, 64);
            a1[0] += __shfl_xor(a1[0], 2, 64);
            a1[0] += __shfl_xor(a1[0], 1, 64);
        }
        if ((lane & 7) == 0) red[wave * KC_A + (lane >> 3)] = a1[0];
        __syncthreads();
        if (tid < KC_A) {
            const float s = red[tid] + red[KC_A + tid] + red[2*KC_A + tid] + red[3*KC_A + tid];
            atomicAdd(&out[b*128 + side*64 + cbase + tid], s);
        }
    }
}

__global__ __launch_bounds__(256) void tpl_kernel(float* __restrict__ out)
{
    __shared__ float red[256];
    float s = 0.f;
    for (int i = threadIdx.x; i < NB*64; i += 256) {
        const int b = i >> 6, k = i & 63;
        const float d = out[b*128 + k] - out[b*128 + 64 + k];
        s = fmaf(d, d, s);
    }
    red[threadIdx.x] = s;
    __syncthreads();
    for (int w = 128; w > 0; w >>= 1) {
        if (threadIdx.x < w) red[threadIdx.x] += red[threadIdx.x + w];
        __syncthreads();
    }
    if (threadIdx.x == 0) out[NB*128] = -red[0];
}

extern "C" void kernel_launch(void* const* d_in, const int* in_sizes, int n_in,
                              void* d_out, int out_size, void* d_ws, size_t ws_size,
                              hipStream_t stream) {
    const float* up0     = (const float*)d_in[0];
    const float* down0   = (const float*)d_in[1];
    const float* ext0    = (const float*)d_in[2];
    const float* ext1    = (const float*)d_in[3];
    const float* centers = (const float*)d_in[4];
    const float* radius  = (const float*)d_in[5];
    float* out = (float*)d_out;

    // accumulator region must start at zero (harness poisons d_out with 0xAA)
    hipMemsetAsync(out, 0, NB * 128 * sizeof(float), stream);

    hat_kernel<<<dim3(256 + 2048), dim3(256), 0, stream>>>(
        up0, down0, ext0, ext1, centers, radius, out);
    tpl_kernel<<<1, 256, 0, stream>>>(out);
}

// Round 12
// 109.574 us; speedup vs baseline: 1.3822x; 1.0290x over previous
//
#include <hip/hip_runtime.h>

#define NB 32
#define N0 20000
#define N1 10000
#define N2 10000
#define KC_A 8
#define KC_B 16
#define NBINS 4096
#define SENT 3.0e4f        // sentinel coord: per-pair contribution ~ -1e-10

__device__ __forceinline__ float sgpr(float x) {
    return __int_as_float(__builtin_amdgcn_readfirstlane(__float_as_int(x)));
}

// grid = 256 B-role blocks (binned ext 1-D part) + 2048 A-role blocks
// (exact beta_0, 4 points/lane, 1 rcp per 4 pairs). atomicAdd into out[0..4095].
__global__ __launch_bounds__(256, 8) void hat_kernel(
    const float* __restrict__ up0, const float* __restrict__ down0,
    const float* __restrict__ ext0, const float* __restrict__ ext1,
    const float* __restrict__ centers, const float* __restrict__ radius,
    float* __restrict__ out)
{
    const int tid  = threadIdx.x;
    const int lane = tid & 63;
    const int wave = tid >> 6;
    const float r  = sgpr(fabsf(radius[0]));
    const float nr = -r;

    __shared__ unsigned hist[NBINS];     // 16 KB (B-role only)
    __shared__ float    red[4 * KC_B];

    if (blockIdx.x < 256) {
        // ================= B-role: ext points, 1-D binned (R9/R11-validated) =
        const int id   = blockIdx.x;
        const int cc   = id & 3;
        const int side = (id >> 2) & 1;
        const int b    = id >> 3;
        const int cbase = cc * KC_B;

        for (int j = tid; j < NBINS; j += 256) hist[j] = 0;
        __syncthreads();

        const float2* e0 = (const float2*)(ext0 + (size_t)b * (N1*2));
        const float2* e1 = (const float2*)(ext1 + (size_t)b * (N2*2));
        for (int i = tid; i < N1; i += 256) {
            const float2 q0 = e0[i];
            const float2 q1 = e1[i];
            const float vv0 = (side == 0) ? q0.y : q0.x;
            const float vv1 = (side == 0) ? q1.y : q1.x;
            int b0 = (int)(vv0 * (float)NBINS);
            int b1 = (int)(vv1 * (float)NBINS);
            b0 = min(max(b0, 0), NBINS - 1);
            b1 = min(max(b1, 0), NBINS - 1);
            atomicAdd(&hist[b0], 1u);
            atomicAdd(&hist[b1], 1u);
        }
        __syncthreads();

        float Ak[KC_B], mk[KC_B];
        #pragma unroll
        for (int k = 0; k < KC_B; ++k) {
            const float cx = centers[2*(cbase+k)];
            const float cy = centers[2*(cbase+k)+1];
            Ak[k] = sgpr(fabsf(1.0f - (cx + cy)));
            mk[k] = sgpr(0.5f * (1.0f + (cx - cy)));
        }

        float part[KC_B];
        #pragma unroll
        for (int k = 0; k < KC_B; ++k) part[k] = 0.f;

        #pragma unroll
        for (int jj = 0; jj < NBINS/256; ++jj) {
            const int j = jj*256 + tid;
            const float cntf = (float)hist[j];
            const float vvj  = ((float)j + 0.5f) * (1.0f/(float)NBINS);
            #pragma unroll
            for (int k = 0; k < KC_B; ++k) {
                const float s  = vvj - mk[k];
                const float tt = fmaxf(Ak[k], 2.0f*fabsf(s));
                const float d1 = 1.0f + tt;
                const float rn = r - tt;
                const float d2 = 1.0f + fabsf(rn);
                const float rc = __builtin_amdgcn_rcpf(d1 * d2);
                part[k] = fmaf(cntf * (d2 - d1), rc, part[k]);
            }
        }

        // KC=16 butterfly (R6-validated)
        {
            #pragma unroll
            for (int k = 0; k < 8; ++k) {
                const bool hi = lane & 32;
                const float send = hi ? part[k]   : part[k+8];
                const float keep = hi ? part[k+8] : part[k];
                part[k] = keep + __shfl_xor(send, 32, 64);
            }
            #pragma unroll
            for (int k = 0; k < 4; ++k) {
                const bool hi = lane & 16;
                const float send = hi ? part[k]   : part[k+4];
                const float keep = hi ? part[k+4] : part[k];
                part[k] = keep + __shfl_xor(send, 16, 64);
            }
            #pragma unroll
            for (int k = 0; k < 2; ++k) {
                const bool hi = lane & 8;
                const float send = hi ? part[k]   : part[k+2];
                const float keep = hi ? part[k+2] : part[k];
                part[k] = keep + __shfl_xor(send, 8, 64);
            }
            {
                const bool hi = lane & 4;
                const float send = hi ? part[0] : part[1];
                const float keep = hi ? part[1] : part[0];
                part[0] = keep + __shfl_xor(send, 4, 64);
            }
            part[0] += __shfl_xor(part[0], 2, 64);
            part[0] += __shfl_xor(part[0], 1, 64);
        }
        if ((lane & 3) == 0) red[wave * KC_B + (lane >> 2)] = part[0];
        __syncthreads();
        if (tid < KC_B) {
            const float s = red[tid] + red[KC_B + tid] + red[2*KC_B + tid] + red[3*KC_B + tid];
            atomicAdd(&out[b*128 + side*64 + cbase + tid], s);
        }
    } else {
        // ===== A-role: beta_0 exact f32, 4 points/lane, 1 rcp / 4 pairs =====
        const int bid    = blockIdx.x - 256;
        const int tchunk = bid & 3;
        const int cc     = (bid >> 2) & 7;
        const int side   = (bid >> 5) & 1;
        const int b      = bid >> 6;
        const int cbase  = cc * KC_A;

        float uc[KC_A], vc[KC_A];
        #pragma unroll
        for (int k = 0; k < KC_A; ++k) {
            const float cx = centers[2*(cbase+k)];
            const float cy = centers[2*(cbase+k)+1];
            uc[k] = sgpr(cx + cy);
            vc[k] = sgpr(cx - cy);
        }

        const float4* base0 = (const float4*)((side == 0 ? up0 : down0) + (size_t)b * (N0*2));

        float acc[KC_A];
        #pragma unroll
        for (int k = 0; k < KC_A; ++k) acc[k] = 0.f;

        // 10000 float4 per (b,side); 2 coalesced float4 (4 pts) per lane/iter;
        // 79*128 = 10112 covers all, remainder -> sentinel.
        for (int t = tchunk*4 + wave; t < 79; t += 16) {
            const int i0 = t*128 + lane;
            const int i1 = i0 + 64;
            float u[4], v[4];
            if (i0 < 10000) {
                const float4 q = base0[i0];
                u[0] = q.x + q.y;  v[0] = q.x - q.y;
                u[1] = q.z + q.w;  v[1] = q.z - q.w;
            } else {
                u[0] = SENT; v[0] = 0.f; u[1] = SENT; v[1] = 0.f;
            }
            if (i1 < 10000) {
                const float4 q = base0[i1];
                u[2] = q.x + q.y;  v[2] = q.x - q.y;
                u[3] = q.z + q.w;  v[3] = q.z - q.w;
            } else {
                u[2] = SENT; v[2] = 0.f; u[3] = SENT; v[3] = 0.f;
            }

            #pragma unroll
            for (int k = 0; k < KC_A; ++k) {
                float dd[4], nm[4];
                #pragma unroll
                for (int p = 0; p < 4; ++p) {
                    const float du = u[p] - uc[k];
                    const float dv = v[p] - vc[k];
                    const float tt = fmaxf(fabsf(du), fabsf(dv)); // L1 via Linf
                    const float d1 = 1.0f + tt;
                    const float n_ = fmaxf(fmaf(-2.0f, tt, r), nr); // |r-n|-n
                    nm[p] = n_;
                    dd[p] = d1 * (d1 + n_);                         // (1+n)(1+|r-n|)
                }
                // sum of 4 fractions with ONE rcp:
                float s01 = nm[0] * dd[1];  s01 = fmaf(nm[1], dd[0], s01);
                float s23 = nm[2] * dd[3];  s23 = fmaf(nm[3], dd[2], s23);
                const float dd01 = dd[0] * dd[1];
                const float dd23 = dd[2] * dd[3];
                float S = s01 * dd23;       S = fmaf(s23, dd01, S);
                const float rc = __builtin_amdgcn_rcpf(dd01 * dd23);
                acc[k] = fmaf(S, rc, acc[k]);
            }
        }

        // KC=8 butterfly (R7/R8-validated)
        float a1[KC_A];
        #pragma unroll
        for (int k = 0; k < KC_A; ++k) a1[k] = acc[k];
        {
            #pragma unroll
            for (int k = 0; k < 4; ++k) {
                const bool hi = lane & 32;
                const float send = hi ? a1[k]   : a1[k+4];
                const float keep = hi ? a1[k+4] : a1[k];
                a1[k] = keep + __shfl_xor(send, 32, 64);
            }
            #pragma unroll
            for (int k = 0; k < 2; ++k) {
                const bool hi = lane & 16;
                const float send = hi ? a1[k]   : a1[k+2];
                const float keep = hi ? a1[k+2] : a1[k];
                a1[k] = keep + __shfl_xor(send, 16, 64);
            }
            {
                const bool hi = lane & 8;
                const float send = hi ? a1[0] : a1[1];
                const float keep = hi ? a1[1] : a1[0];
                a1[0] = keep + __shfl_xor(send, 8, 64);
            }
            a1[0] += __shfl_xor(a1[0], 4, 64);
            a1[0] += __shfl_xor(a1[0], 2, 64);
            a1[0] += __shfl_xor(a1[0], 1, 64);
        }
        if ((lane & 7) == 0) red[wave * KC_A + (lane >> 3)] = a1[0];
        __syncthreads();
        if (tid < KC_A) {
            const float s = red[tid] + red[KC_A + tid] + red[2*KC_A + tid] + red[3*KC_A + tid];
            atomicAdd(&out[b*128 + side*64 + cbase + tid], s);
        }
    }
}

__global__ __launch_bounds__(256) void tpl_kernel(float* __restrict__ out)
{
    __shared__ float red[256];
    float s = 0.f;
    for (int i = threadIdx.x; i < NB*64; i += 256) {
        const int b = i >> 6, k = i & 63;
        const float d = out[b*128 + k] - out[b*128 + 64 + k];
        s = fmaf(d, d, s);
    }
    red[threadIdx.x] = s;
    __syncthreads();
    for (int w = 128; w > 0; w >>= 1) {
        if (threadIdx.x < w) red[threadIdx.x] += red[threadIdx.x + w];
        __syncthreads();
    }
    if (threadIdx.x == 0) out[NB*128] = -red[0];
}

extern "C" void kernel_launch(void* const* d_in, const int* in_sizes, int n_in,
                              void* d_out, int out_size, void* d_ws, size_t ws_size,
                              hipStream_t stream) {
    const float* up0     = (const float*)d_in[0];
    const float* down0   = (const float*)d_in[1];
    const float* ext0    = (const float*)d_in[2];
    const float* ext1    = (const float*)d_in[3];
    const float* centers = (const float*)d_in[4];
    const float* radius  = (const float*)d_in[5];
    float* out = (float*)d_out;

    // accumulator region must start at zero (harness poisons d_out with 0xAA)
    hipMemsetAsync(out, 0, NB * 128 * sizeof(float), stream);

    hat_kernel<<<dim3(256 + 2048), dim3(256), 0, stream>>>(
        up0, down0, ext0, ext1, centers, radius, out);
    tpl_kernel<<<1, 256, 0, stream>>>(out);
}